// Round 1
// 265.477 us; speedup vs baseline: 1.0089x; 1.0089x over previous
//
#include <hip/hip_runtime.h>

#define DEV_INLINE __device__ __forceinline__

// Problem dims (fixed by setup_inputs)
constexpr int B = 16, T = 4096, C = 512, K = 3;
constexpr int NC = 64;           // chunks along T
constexpr int L  = T / NC;       // 64 steps per chunk
constexpr int C4 = C / 4;        // 128 float4 lanes across channels
constexpr float EPS = 1e-4f;

// ws layout (floats): carry[b][chunk][k][c] local-suffix states -> 6.29 MB
//   K1 writes chunk-local suffixes (zero-init EMA; chunk 0 is x0-init, exact).
//   K2 re-derives each chunk's incoming state by scanning carries of chunks < i.

typedef float f4v __attribute__((ext_vector_type(4)));

DEV_INLINE float4 f4mul(float4 a, float4 b) {
  return make_float4(a.x * b.x, a.y * b.y, a.z * b.z, a.w * b.w);
}
DEV_INLINE float4 f4fma(float4 a, float4 b, float4 c) {
  return make_float4(fmaf(a.x, b.x, c.x), fmaf(a.y, b.y, c.y),
                     fmaf(a.z, b.z, c.z), fmaf(a.w, b.w, c.w));
}
DEV_INLINE float4 f4onesub(float4 a) {
  return make_float4(1.f - a.x, 1.f - a.y, 1.f - a.z, 1.f - a.w);
}

DEV_INLINE float sig_clamp(float v) {
  float a = 1.0f / (1.0f + __expf(-v));
  return fminf(fmaxf(a, EPS), 1.0f - EPS);
}
DEV_INLINE float4 sig4(float4 v) {
  return make_float4(sig_clamp(v.x), sig_clamp(v.y), sig_clamp(v.z), sig_clamp(v.w));
}

DEV_INLINE void sm3(float l0, float l1, float l2, float& o0, float& o1, float& o2) {
  float mx = fmaxf(l0, fmaxf(l1, l2));
  float e0 = __expf(l0 - mx), e1 = __expf(l1 - mx), e2 = __expf(l2 - mx);
  float inv = 1.0f / (e0 + e1 + e2);
  o0 = e0 * inv; o1 = e1 * inv; o2 = e2 * inv;
}

// nontemporal float4 store: out is write-once streaming; nt keeps it from
// evicting x (134 MB) out of the 256 MB Infinity Cache between K1 and K2 reads.
DEV_INLINE void nt_store(float4* p, float4 v) {
  f4v t; t.x = v.x; t.y = v.y; t.z = v.z; t.w = v.w;
  __builtin_nontemporal_store(t, reinterpret_cast<f4v*>(p));
}

// ---------------- K1: fused prep + per-chunk local suffix ----------------
__global__ __launch_bounds__(128) void ema_k1(const float* __restrict__ x,
                                              const float* __restrict__ logit_alpha,
                                              float* __restrict__ carry_f) {
  const int c4 = threadIdx.x;          // 0..C4-1
  const int bi = blockIdx.x;           // b*NC + chunk
  const int i  = bi & (NC - 1);

  // per-block recompute of a,b (replaces ema_prep; ~12 exps/thread)
  const float4* la = (const float4*)logit_alpha;
  const float4 a0 = sig4(la[0 * C4 + c4]);
  const float4 a1 = sig4(la[1 * C4 + c4]);
  const float4 a2 = sig4(la[2 * C4 + c4]);
  const float4 b0 = f4onesub(a0), b1 = f4onesub(a1), b2 = f4onesub(a2);

  const float4* xb = (const float4*)x + (size_t)bi * L * C4 + c4;

  float4 y0, y1, y2;
  int jstart;
  if (i == 0) {
    // chunk 0: y[0] = x[0] exactly (no incoming state)
    float4 x0 = xb[0];
    y0 = x0; y1 = x0; y2 = x0;
    jstart = 1;
  } else {
    y0 = make_float4(0.f, 0.f, 0.f, 0.f);
    y1 = y0; y2 = y0;
    jstart = 0;
  }

  #pragma unroll 4
  for (int j = jstart; j < L; ++j) {
    float4 xv = xb[(size_t)j * C4];
    y0 = f4fma(a0, y0, f4mul(b0, xv));
    y1 = f4fma(a1, y1, f4mul(b1, xv));
    y2 = f4fma(a2, y2, f4mul(b2, xv));
  }

  float4* carry = (float4*)carry_f;
  const size_t cb = (size_t)bi * (K * C4) + c4;
  carry[cb + 0 * C4] = y0;
  carry[cb + 1 * C4] = y1;
  carry[cb + 2 * C4] = y2;
}

// ---------------- K2: inline carry-scan + recurrence + mix, streamed out ----------------
__global__ __launch_bounds__(128) void ema_k2(const float* __restrict__ x,
                                              const float* __restrict__ logit_alpha,
                                              const float* __restrict__ mix_logits,
                                              const float* __restrict__ carry_f,
                                              float* __restrict__ out) {
  const int c4 = threadIdx.x;
  const int bi = blockIdx.x;
  const int i  = bi & (NC - 1);
  const int b  = bi >> 6;              // NC = 64

  const float4* la = (const float4*)logit_alpha;
  const float4 a0 = sig4(la[0 * C4 + c4]);
  const float4 a1 = sig4(la[1 * C4 + c4]);
  const float4 a2 = sig4(la[2 * C4 + c4]);
  const float4 b0 = f4onesub(a0), b1 = f4onesub(a1), b2 = f4onesub(a2);

  // mix softmax: channels 4*c4 .. 4*c4+3; mix_logits is [C][K], 12 floats/thread
  const float4* ml = (const float4*)mix_logits;
  const float4 q0 = ml[3 * c4 + 0];
  const float4 q1 = ml[3 * c4 + 1];
  const float4 q2 = ml[3 * c4 + 2];
  float4 m0, m1, m2;
  sm3(q0.x, q0.y, q0.z, m0.x, m1.x, m2.x);
  sm3(q0.w, q1.x, q1.y, m0.y, m1.y, m2.y);
  sm3(q1.z, q1.w, q2.x, m0.z, m1.z, m2.z);
  sm3(q2.y, q2.z, q2.w, m0.w, m1.w, m2.w);

  const float4* xb = (const float4*)x + (size_t)bi * L * C4 + c4;
  float4*       ob = (float4*)out     + (size_t)bi * L * C4 + c4;

  float4 y0, y1, y2;
  int jstart;
  if (i == 0) {
    float4 x0 = xb[0];
    y0 = x0; y1 = x0; y2 = x0;
    nt_store(&ob[0], f4fma(m0, y0, f4fma(m1, y1, f4mul(m2, y2))));
    jstart = 1;
  } else {
    // A = a^L via 6 squarings (L = 64)
    float4 A0 = a0, A1 = a1, A2 = a2;
    #pragma unroll
    for (int s = 0; s < 6; ++s) { A0 = f4mul(A0, A0); A1 = f4mul(A1, A1); A2 = f4mul(A2, A2); }

    // incoming state for chunk i = E_{i-1}; E_0 = s_0, E_j = A*E_{j-1} + s_j
    // (identical fma order to the old sequential pass2 -> bitwise-identical states)
    const size_t stride = (size_t)K * C4;
    const float4* cb = (const float4*)carry_f + (size_t)b * NC * stride + c4;
    y0 = cb[0 * C4];
    y1 = cb[1 * C4];
    y2 = cb[2 * C4];
    #pragma unroll 4
    for (int j = 1; j < i; ++j) {
      const float4* cj = cb + (size_t)j * stride;
      y0 = f4fma(A0, y0, cj[0 * C4]);
      y1 = f4fma(A1, y1, cj[1 * C4]);
      y2 = f4fma(A2, y2, cj[2 * C4]);
    }
    jstart = 0;
  }

  #pragma unroll 4
  for (int j = jstart; j < L; ++j) {
    float4 xv = xb[(size_t)j * C4];
    y0 = f4fma(a0, y0, f4mul(b0, xv));
    y1 = f4fma(a1, y1, f4mul(b1, xv));
    y2 = f4fma(a2, y2, f4mul(b2, xv));
    nt_store(&ob[(size_t)j * C4], f4fma(m0, y0, f4fma(m1, y1, f4mul(m2, y2))));
  }
}

extern "C" void kernel_launch(void* const* d_in, const int* in_sizes, int n_in,
                              void* d_out, int out_size, void* d_ws, size_t ws_size,
                              hipStream_t stream) {
  const float* x           = (const float*)d_in[0];
  const float* logit_alpha = (const float*)d_in[1];
  const float* mix_logits  = (const float*)d_in[2];
  float* out = (float*)d_out;
  float* ws  = (float*)d_ws;

  ema_k1<<<B * NC, 128, 0, stream>>>(x, logit_alpha, ws);
  ema_k2<<<B * NC, 128, 0, stream>>>(x, logit_alpha, mix_logits, ws, out);
}